// Round 2
// baseline (831.510 us; speedup 1.0000x reference)
//
#include <hip/hip_runtime.h>
#include <math.h>

// Problem constants (from reference)
constexpr int NQ = 4096, NK = 1024, CIN = 128, CKV = 256, E = 128, H = 8, D = 16, LAYERS = 3;
constexpr float SCALE = 1.0f / 256.0f;      // 1 / D^2
constexpr float CLAMP_MAX = 65503.0f;

__device__ __forceinline__ float dot4(float4 a, float4 b) {
  return a.x * b.x + a.y * b.y + a.z * b.z + a.w * b.w;
}

// ---------------- block reduction helper (256 threads, 4 waves) ----------------
__device__ __forceinline__ void block_reduce2(float& a, float& b, float* red) {
#pragma unroll
  for (int off = 32; off > 0; off >>= 1) {
    a += __shfl_down(a, off, 64);
    b += __shfl_down(b, off, 64);
  }
  int lane = threadIdx.x & 63, wid = threadIdx.x >> 6;
  if (lane == 0) { red[wid * 2] = a; red[wid * 2 + 1] = b; }
  __syncthreads();
  if (threadIdx.x == 0) {
    float sa = 0.f, sb = 0.f;
#pragma unroll
    for (int w = 0; w < 4; w++) { sa += red[w * 2]; sb += red[w * 2 + 1]; }
    red[0] = sa; red[1] = sb;
  }
  __syncthreads();
  a = red[0]; b = red[1];
}

// ---------------- GroupNorm: partial sums (2048 floats per block) ----------------
__global__ __launch_bounds__(256) void gn_partial(const float* __restrict__ in,
                                                  float* __restrict__ partials) {
  __shared__ float red[8];
  const float4* p = (const float4*)in + (size_t)blockIdx.x * 512;
  float s = 0.f, sq = 0.f;
#pragma unroll
  for (int i = 0; i < 2; i++) {
    float4 v = p[threadIdx.x + i * 256];
    s += v.x + v.y + v.z + v.w;
    sq += v.x * v.x + v.y * v.y + v.z * v.z + v.w * v.w;
  }
  block_reduce2(s, sq, red);
  if (threadIdx.x == 0) {
    partials[blockIdx.x * 2] = s;
    partials[blockIdx.x * 2 + 1] = sq;
  }
}

// ---------------- GroupNorm: finalize per-group stats ----------------
__global__ __launch_bounds__(64) void gn_finalize(const float* __restrict__ partials,
                                                  float* __restrict__ stats, int bpg,
                                                  float inv_n) {
  int g = blockIdx.x, lane = threadIdx.x;
  float s = 0.f, sq = 0.f;
  if (lane < bpg) {
    s = partials[(g * bpg + lane) * 2];
    sq = partials[(g * bpg + lane) * 2 + 1];
  }
#pragma unroll
  for (int off = 32; off > 0; off >>= 1) {
    s += __shfl_down(s, off, 64);
    sq += __shfl_down(sq, off, 64);
  }
  if (lane == 0) {
    float mu = s * inv_n;
    float var = sq * inv_n - mu * mu;
    stats[g * 2] = mu;
    stats[g * 2 + 1] = rsqrtf(var + 1e-5f);
  }
}

// ---------------- GroupNorm: apply (+optional ReLU) ----------------
__global__ __launch_bounds__(256) void gn_apply(const float* __restrict__ in,
                                                float* __restrict__ out,
                                                const float* __restrict__ stats,
                                                const float* __restrict__ w,
                                                const float* __restrict__ b,
                                                int n4, int epg4, int relu) {
  int f = blockIdx.x * 256 + threadIdx.x;
  int c = f / n4;       // flat channel index (matches flat w/b layout)
  int g = f / epg4;     // flat group index
  float mu = stats[2 * g], rs = stats[2 * g + 1];
  float sc = w[c] * rs, sh = b[c] - mu * sc;
  float4 v = ((const float4*)in)[f];
  float4 o;
  o.x = v.x * sc + sh; o.y = v.y * sc + sh; o.z = v.z * sc + sh; o.w = v.w * sc + sh;
  if (relu) {
    o.x = fmaxf(o.x, 0.f); o.y = fmaxf(o.y, 0.f);
    o.z = fmaxf(o.z, 0.f); o.w = fmaxf(o.w, 0.f);
  }
  ((float4*)out)[f] = o;
}

// ---------------- 1x1-conv projection: out[l][e][n] = sum_c W[l,e,c]*in[(l),c,n] + B[l,e] ----
__global__ __launch_bounds__(256) void proj_kernel(const float* __restrict__ in,
                                                   const float* __restrict__ W,
                                                   const float* __restrict__ B,
                                                   float* __restrict__ out,
                                                   int Cin, int N, int per_l) {
  int f = blockIdx.x * 256 + threadIdx.x;
  int n4c = N >> 2;
  int n0 = (f % n4c) * 4;
  int e0 = ((f / n4c) & 31) * 4;
  int l = f / (n4c * 32);
  const float* inl = in + (per_l ? (size_t)l * Cin * N : 0);
  const float* Wl = W + (size_t)l * E * Cin;
  float4 acc[4];
#pragma unroll
  for (int i = 0; i < 4; i++) acc[i] = make_float4(0.f, 0.f, 0.f, 0.f);
  for (int c = 0; c < Cin; c++) {
    float4 v = *(const float4*)(inl + (size_t)c * N + n0);
    float wv[4];
#pragma unroll
    for (int i = 0; i < 4; i++) wv[i] = Wl[(e0 + i) * Cin + c];
#pragma unroll
    for (int i = 0; i < 4; i++) {
      acc[i].x += wv[i] * v.x; acc[i].y += wv[i] * v.y;
      acc[i].z += wv[i] * v.z; acc[i].w += wv[i] * v.w;
    }
  }
#pragma unroll
  for (int i = 0; i < 4; i++) {
    float bv = B[l * E + e0 + i];
    acc[i].x += bv; acc[i].y += bv; acc[i].z += bv; acc[i].w += bv;
    *(float4*)(out + ((size_t)l * E + e0 + i) * N + n0) = acc[i];
  }
}

// ---------------- fused attention: score + softmax + PV (+w_att write for l==2) ------------
// One block per (8-query tile, head, layer). 256 threads.
constexpr int QT = 8;
constexpr int SSTR = 1032;   // dwords per P row (1024 + 8 pad)

__global__ __launch_bounds__(256, 4) void attn_kernel(const float* __restrict__ qn,
                                                      const float* __restrict__ kn,
                                                      const float* __restrict__ vn,
                                                      float* __restrict__ ob,
                                                      float* __restrict__ wout) {
  __shared__ float S[QT * SSTR];       // 33 KB: P = exp(s - m)
  __shared__ float red[8 * 128];       // ksl partial O
  __shared__ float pmax[4 * QT];
  __shared__ float psum[4 * QT];
  __shared__ float rowinv[QT];

  int t = threadIdx.x;
  int q0 = blockIdx.x * QT;
  int h = blockIdx.y;
  int l = blockIdx.z;

  const float* Qb = qn + ((size_t)l * E + h * D) * NQ;   // [d][n]
  const float* Kb = kn + ((size_t)l * E + h * D) * NK;   // [d][k]
  const float* Vb = vn + ((size_t)l * E + h * D) * NK;   // [d][k]

  int q = t & 7;
  int ks = t >> 3;      // 0..31
  int wid = t >> 6;

  // Q tile into registers (redundant across ks groups; L1-served)
  float qreg[16];
#pragma unroll
  for (int d = 0; d < 16; d++) qreg[d] = Qb[d * NQ + q0 + q];

  // ---- phase 1: scores for k = ks*4 + 128*j into registers ----
  float4 sreg[8];
#pragma unroll
  for (int j = 0; j < 8; j++) {
    int k = ks * 4 + j * 128;
    float4 a = make_float4(0.f, 0.f, 0.f, 0.f);
#pragma unroll
    for (int d = 0; d < 16; d++) {
      float4 kv = *(const float4*)(Kb + d * NK + k);
      a.x += qreg[d] * kv.x; a.y += qreg[d] * kv.y;
      a.z += qreg[d] * kv.z; a.w += qreg[d] * kv.w;
    }
    a.x = fminf(a.x * SCALE, CLAMP_MAX);
    a.y = fminf(a.y * SCALE, CLAMP_MAX);
    a.z = fminf(a.z * SCALE, CLAMP_MAX);
    a.w = fminf(a.w * SCALE, CLAMP_MAX);
    sreg[j] = a;
  }

  // ---- phase 2: softmax (row max, exp, row sum) ----
  float m = -3.0e38f;
#pragma unroll
  for (int j = 0; j < 8; j++) {
    m = fmaxf(m, fmaxf(fmaxf(sreg[j].x, sreg[j].y), fmaxf(sreg[j].z, sreg[j].w)));
  }
  m = fmaxf(m, __shfl_xor(m, 8, 64));
  m = fmaxf(m, __shfl_xor(m, 16, 64));
  m = fmaxf(m, __shfl_xor(m, 32, 64));
  if ((t & 63) < 8) pmax[wid * 8 + q] = m;
  __syncthreads();
  float gm = fmaxf(fmaxf(pmax[q], pmax[8 + q]), fmaxf(pmax[16 + q], pmax[24 + q]));

  float s = 0.f;
#pragma unroll
  for (int j = 0; j < 8; j++) {
    sreg[j].x = __expf(sreg[j].x - gm);
    sreg[j].y = __expf(sreg[j].y - gm);
    sreg[j].z = __expf(sreg[j].z - gm);
    sreg[j].w = __expf(sreg[j].w - gm);
    s += sreg[j].x + sreg[j].y + sreg[j].z + sreg[j].w;
  }
  s += __shfl_xor(s, 8, 64);
  s += __shfl_xor(s, 16, 64);
  s += __shfl_xor(s, 32, 64);
  if ((t & 63) < 8) psum[wid * 8 + q] = s;
  __syncthreads();
  float gs = psum[q] + psum[8 + q] + psum[16 + q] + psum[24 + q];
  float rinv = 1.f / gs;
  if (t < 8) rowinv[t] = 1.f / (psum[t] + psum[8 + t] + psum[16 + t] + psum[24 + t]);

  // store P (unnormalized) to LDS
#pragma unroll
  for (int j = 0; j < 8; j++) {
    *(float4*)(S + q * SSTR + ks * 4 + j * 128) = sreg[j];
  }
  __syncthreads();

  // ---- w_att output (layer 2 only): W = P * rowinv ----
  if (wout) {
#pragma unroll
    for (int r = 0; r < QT; r++) {
      float4 p = *(const float4*)(S + r * SSTR + 4 * t);
      float ri = rowinv[r];
      p.x *= ri; p.y *= ri; p.z *= ri; p.w *= ri;
      *(float4*)(wout + ((size_t)h * NQ + q0 + r) * NK + 4 * t) = p;
    }
  }

  // ---- phase 3: O[q][d] = rinv * sum_k P[q][k] V[d][k] ----
  int dg = (t >> 3) & 3;
  int ksl = t >> 5;             // 0..7, 128 k each
  const float* V0 = Vb + (size_t)(dg * 4 + 0) * NK;
  const float* V1 = Vb + (size_t)(dg * 4 + 1) * NK;
  const float* V2 = Vb + (size_t)(dg * 4 + 2) * NK;
  const float* V3 = Vb + (size_t)(dg * 4 + 3) * NK;
  float4 a0 = make_float4(0.f, 0.f, 0.f, 0.f), a1 = a0, a2 = a0, a3 = a0;
#pragma unroll 8
  for (int j = 0; j < 32; j++) {
    int k = ksl * 128 + j * 4;
    float4 p = *(const float4*)(S + q * SSTR + k);
    float4 v0 = *(const float4*)(V0 + k);
    float4 v1 = *(const float4*)(V1 + k);
    float4 v2 = *(const float4*)(V2 + k);
    float4 v3 = *(const float4*)(V3 + k);
    a0.x += p.x * v0.x; a0.y += p.y * v0.y; a0.z += p.z * v0.z; a0.w += p.w * v0.w;
    a1.x += p.x * v1.x; a1.y += p.y * v1.y; a1.z += p.z * v1.z; a1.w += p.w * v1.w;
    a2.x += p.x * v2.x; a2.y += p.y * v2.y; a2.z += p.z * v2.z; a2.w += p.w * v2.w;
    a3.x += p.x * v3.x; a3.y += p.y * v3.y; a3.z += p.z * v3.z; a3.w += p.w * v3.w;
  }
  float4 part = make_float4(dot4(a0, make_float4(1, 1, 1, 1)) * 0.f + (a0.x + a0.y + a0.z + a0.w),
                            a1.x + a1.y + a1.z + a1.w,
                            a2.x + a2.y + a2.z + a2.w,
                            a3.x + a3.y + a3.z + a3.w);
  *(float4*)(red + ksl * 128 + q * 16 + dg * 4) = part;
  __syncthreads();
  if (t < 128) {
    int d = t >> 3, qq = t & 7;
    float o = 0.f;
#pragma unroll
    for (int s2 = 0; s2 < 8; s2++) o += red[s2 * 128 + qq * 16 + d];
    o *= rowinv[qq];
    ob[((size_t)l * E + h * D + d) * NQ + q0 + qq] = o;
  }
  (void)rinv;
}

// ---------------- combine partials: pc[l][c][n] = sum_e cw[l,c,e] * ob[l,e,n] ----------------
__global__ __launch_bounds__(256) void combine_partial(const float* __restrict__ ob,
                                                       const float* __restrict__ cw,
                                                       float* __restrict__ pc) {
  int f = blockIdx.x * 256 + threadIdx.x;
  int n0 = (f & 1023) * 4;
  int c0 = ((f >> 10) & 31) * 4;
  int l = f >> 15;
  const float* obl = ob + (size_t)l * E * NQ;
  const float* cwl = cw + (size_t)l * CIN * E;
  float4 acc[4];
#pragma unroll
  for (int i = 0; i < 4; i++) acc[i] = make_float4(0.f, 0.f, 0.f, 0.f);
#pragma unroll 4
  for (int e = 0; e < E; e++) {
    float4 ov = *(const float4*)(obl + (size_t)e * NQ + n0);
    float wv[4];
#pragma unroll
    for (int i = 0; i < 4; i++) wv[i] = cwl[(c0 + i) * E + e];
#pragma unroll
    for (int i = 0; i < 4; i++) {
      acc[i].x += wv[i] * ov.x; acc[i].y += wv[i] * ov.y;
      acc[i].z += wv[i] * ov.z; acc[i].w += wv[i] * ov.w;
    }
  }
#pragma unroll
  for (int i = 0; i < 4; i++) {
    *(float4*)(pc + ((size_t)l * CIN + c0 + i) * NQ + n0) = acc[i];
  }
}

// ---------------- final: out = x + xq + (1/3)(sum_l pc + sum_l cb) ----------------
__global__ __launch_bounds__(256) void combine_final(const float* __restrict__ x,
                                                     const float* __restrict__ xq,
                                                     const float* __restrict__ pc,
                                                     const float* __restrict__ cb,
                                                     float* __restrict__ out) {
  int f = blockIdx.x * 256 + threadIdx.x;
  int n0 = (f & 1023) * 4;
  int c = f >> 10;
  const float third = 1.f / 3.f;
  float bsum = (cb[c] + cb[CIN + c] + cb[2 * CIN + c]) * third;
  size_t off = (size_t)c * NQ + n0;
  float4 p0 = *(const float4*)(pc + off);
  float4 p1 = *(const float4*)(pc + (size_t)CIN * NQ + off);
  float4 p2 = *(const float4*)(pc + (size_t)2 * CIN * NQ + off);
  float4 xv = *(const float4*)(x + off);
  float4 xqv = *(const float4*)(xq + off);
  float4 o;
  o.x = xv.x + xqv.x + (p0.x + p1.x + p2.x) * third + bsum;
  o.y = xv.y + xqv.y + (p0.y + p1.y + p2.y) * third + bsum;
  o.z = xv.z + xqv.z + (p0.z + p1.z + p2.z) * third + bsum;
  o.w = xv.w + xqv.w + (p0.w + p1.w + p2.w) * third + bsum;
  *(float4*)(out + off) = o;
}

extern "C" void kernel_launch(void* const* d_in, const int* in_sizes, int n_in,
                              void* d_out, int out_size, void* d_ws, size_t ws_size,
                              hipStream_t stream) {
  (void)in_sizes; (void)n_in; (void)out_size;
  const float* x    = (const float*)d_in[0];
  const float* xgi  = (const float*)d_in[1];
  const float* gn1w = (const float*)d_in[4];
  const float* gn1b = (const float*)d_in[5];
  const float* gn2w = (const float*)d_in[6];
  const float* gn2b = (const float*)d_in[7];
  const float* qw   = (const float*)d_in[8];
  const float* qb   = (const float*)d_in[9];
  const float* kw   = (const float*)d_in[10];
  const float* kb   = (const float*)d_in[11];
  const float* vw   = (const float*)d_in[12];
  const float* vb   = (const float*)d_in[13];
  const float* qgnw = (const float*)d_in[14];
  const float* qgnb = (const float*)d_in[15];
  const float* cw   = (const float*)d_in[16];
  const float* cb   = (const float*)d_in[17];

  float* ws = (float*)d_ws;
  float* xq    = ws;                 // 524288   [c][n]
  float* xgb   = ws + 524288;        // 786432   [l][c][n]
  float* qn    = ws + 1310720;       // 1572864  [l][e][n]
  float* kn    = ws + 2883584;       // 393216   [l][e][k]
  float* vn    = ws + 3276800;       // 393216   [l][e][k]
  float* ob    = ws + 3670016;       // 1572864  [l][e][n]
  float* part  = ws + 5242880;       // 1536
  float* stats = ws + 5244928;       // 96
  float* pc    = qn;                 // reuse qn region after attention (1572864)
  if (ws_size < (size_t)5245056 * sizeof(float)) return;

  float* outp = (float*)d_out;            // 524288 floats: final out
  float* wout = outp + 524288;            // 33554432 floats: w_att (layer 2)

  // GroupNorm(8) + ReLU on x -> xq
  gn_partial<<<256, 256, 0, stream>>>(x, part);
  gn_finalize<<<8, 64, 0, stream>>>(part, stats, 32, 1.f / 65536.f);
  gn_apply<<<512, 256, 0, stream>>>(x, xq, stats, gn1w, gn1b, 1024, 16384, 1);

  // GroupNorm(16) + ReLU on x_global -> xgb
  gn_partial<<<384, 256, 0, stream>>>(xgi, part);
  gn_finalize<<<48, 64, 0, stream>>>(part, stats, 8, 1.f / 16384.f);
  gn_apply<<<768, 256, 0, stream>>>(xgi, xgb, stats, gn2w, gn2b, 256, 4096, 1);

  // projections
  proj_kernel<<<384, 256, 0, stream>>>(xq, qw, qb, qn, 128, 4096, 0);
  proj_kernel<<<96, 256, 0, stream>>>(xgb, kw, kb, kn, 256, 1024, 1);
  proj_kernel<<<96, 256, 0, stream>>>(xgb, vw, vb, vn, 256, 1024, 1);

  // shared GroupNorm(8, qgn) on q, k, v (in place)
  gn_partial<<<768, 256, 0, stream>>>(qn, part);
  gn_finalize<<<24, 64, 0, stream>>>(part, stats, 32, 1.f / 65536.f);
  gn_apply<<<1536, 256, 0, stream>>>(qn, qn, stats, qgnw, qgnb, 1024, 16384, 0);

  gn_partial<<<192, 256, 0, stream>>>(kn, part);
  gn_finalize<<<24, 64, 0, stream>>>(part, stats, 8, 1.f / 16384.f);
  gn_apply<<<384, 256, 0, stream>>>(kn, kn, stats, qgnw, qgnb, 256, 4096, 0);

  gn_partial<<<192, 256, 0, stream>>>(vn, part);
  gn_finalize<<<24, 64, 0, stream>>>(part, stats, 8, 1.f / 16384.f);
  gn_apply<<<384, 256, 0, stream>>>(vn, vn, stats, qgnw, qgnb, 256, 4096, 0);

  // fused attention for all layers; layer 2 writes w_att
  attn_kernel<<<dim3(512, 8, 3), 256, 0, stream>>>(qn, kn, vn, ob, wout);

  // combine heads + residuals
  combine_partial<<<384, 256, 0, stream>>>(ob, cw, pc);
  combine_final<<<512, 256, 0, stream>>>(x, xq, pc, cb, outp);
}

// Round 3
// 431.697 us; speedup vs baseline: 1.9261x; 1.9261x over previous
//
#include <hip/hip_runtime.h>
#include <math.h>

constexpr int NQ = 4096, NK = 1024, CIN = 128, CKV = 256, E = 128, H = 8, D = 16, LAYERS = 3;
constexpr float SCALE = 1.0f / 256.0f;
constexpr float CLAMP_MAX = 65503.0f;
constexpr float LOG2E = 1.44269504088896340736f;
constexpr float CLAMP2 = CLAMP_MAX * LOG2E;

typedef __bf16 bf16x8 __attribute__((ext_vector_type(8)));
typedef __bf16 bf16x4 __attribute__((ext_vector_type(4)));
typedef float f32x16 __attribute__((ext_vector_type(16)));
typedef float f32x4 __attribute__((ext_vector_type(4)));

__device__ __forceinline__ float exp2_fast(float x) {
#if __has_builtin(__builtin_amdgcn_exp2f)
  return __builtin_amdgcn_exp2f(x);
#else
  return exp2f(x);
#endif
}

// ---------------- block reduction helper (256 threads, 4 waves) ----------------
__device__ __forceinline__ void block_reduce2(float& a, float& b, float* red) {
#pragma unroll
  for (int off = 32; off > 0; off >>= 1) {
    a += __shfl_down(a, off, 64);
    b += __shfl_down(b, off, 64);
  }
  int lane = threadIdx.x & 63, wid = threadIdx.x >> 6;
  if (lane == 0) { red[wid * 2] = a; red[wid * 2 + 1] = b; }
  __syncthreads();
  if (threadIdx.x == 0) {
    float sa = 0.f, sb = 0.f;
#pragma unroll
    for (int w = 0; w < 4; w++) { sa += red[w * 2]; sb += red[w * 2 + 1]; }
    red[0] = sa; red[1] = sb;
  }
  __syncthreads();
  a = red[0]; b = red[1];
}

// ---------------- GroupNorm: partial sums (2048 floats per block) ----------------
__global__ __launch_bounds__(256) void gn_partial(const float* __restrict__ in,
                                                  float* __restrict__ partials) {
  __shared__ float red[8];
  const float4* p = (const float4*)in + (size_t)blockIdx.x * 512;
  float s = 0.f, sq = 0.f;
#pragma unroll
  for (int i = 0; i < 2; i++) {
    float4 v = p[threadIdx.x + i * 256];
    s += v.x + v.y + v.z + v.w;
    sq += v.x * v.x + v.y * v.y + v.z * v.z + v.w * v.w;
  }
  block_reduce2(s, sq, red);
  if (threadIdx.x == 0) {
    partials[blockIdx.x * 2] = s;
    partials[blockIdx.x * 2 + 1] = sq;
  }
}

// ---------------- GroupNorm: finalize (uniform bpg) ----------------
__global__ __launch_bounds__(64) void gn_finalize(const float* __restrict__ partials,
                                                  float* __restrict__ stats, int bpg,
                                                  float inv_n) {
  int g = blockIdx.x, lane = threadIdx.x;
  float s = 0.f, sq = 0.f;
  if (lane < bpg) {
    s = partials[(g * bpg + lane) * 2];
    sq = partials[(g * bpg + lane) * 2 + 1];
  }
#pragma unroll
  for (int off = 32; off > 0; off >>= 1) {
    s += __shfl_down(s, off, 64);
    sq += __shfl_down(sq, off, 64);
  }
  if (lane == 0) {
    float mu = s * inv_n;
    float var = sq * inv_n - mu * mu;
    stats[g * 2] = mu;
    stats[g * 2 + 1] = rsqrtf(var + 1e-5f);
  }
}

// ---------------- GroupNorm finalize for q/k/v (72 groups, mixed sizes) ----------------
__global__ __launch_bounds__(64) void gn_finalize72(const float* __restrict__ partials,
                                                    float* __restrict__ stats) {
  int g = blockIdx.x, lane = threadIdx.x;
  int bpg, poff; float inv;
  if (g < 24)      { bpg = 32; poff = g * 32;            inv = 1.f / 65536.f; }
  else if (g < 48) { bpg = 8;  poff = 768 + (g - 24) * 8; inv = 1.f / 16384.f; }
  else             { bpg = 8;  poff = 960 + (g - 48) * 8; inv = 1.f / 16384.f; }
  float s = 0.f, sq = 0.f;
  if (lane < bpg) {
    s = partials[(poff + lane) * 2];
    sq = partials[(poff + lane) * 2 + 1];
  }
#pragma unroll
  for (int off = 32; off > 0; off >>= 1) {
    s += __shfl_down(s, off, 64);
    sq += __shfl_down(sq, off, 64);
  }
  if (lane == 0) {
    float mu = s * inv;
    float var = sq * inv - mu * mu;
    stats[g * 2] = mu;
    stats[g * 2 + 1] = rsqrtf(var + 1e-5f);
  }
}

// ---------------- GroupNorm: apply (+optional ReLU), fp32 out ----------------
__global__ __launch_bounds__(256) void gn_apply(const float* __restrict__ in,
                                                float* __restrict__ out,
                                                const float* __restrict__ stats,
                                                const float* __restrict__ w,
                                                const float* __restrict__ b,
                                                int n4, int epg4, int relu) {
  int f = blockIdx.x * 256 + threadIdx.x;
  int c = f / n4;
  int g = f / epg4;
  float mu = stats[2 * g], rs = stats[2 * g + 1];
  float sc = w[c] * rs, sh = b[c] - mu * sc;
  float4 v = ((const float4*)in)[f];
  float4 o;
  o.x = v.x * sc + sh; o.y = v.y * sc + sh; o.z = v.z * sc + sh; o.w = v.w * sc + sh;
  if (relu) {
    o.x = fmaxf(o.x, 0.f); o.y = fmaxf(o.y, 0.f);
    o.z = fmaxf(o.z, 0.f); o.w = fmaxf(o.w, 0.f);
  }
  ((float4*)out)[f] = o;
}

// ---------------- 1x1-conv projection ----------------
__global__ __launch_bounds__(256) void proj_kernel(const float* __restrict__ in,
                                                   const float* __restrict__ W,
                                                   const float* __restrict__ B,
                                                   float* __restrict__ out,
                                                   int Cin, int N, int per_l) {
  int f = blockIdx.x * 256 + threadIdx.x;
  int n4c = N >> 2;
  int n0 = (f % n4c) * 4;
  int e0 = ((f / n4c) & 31) * 4;
  int l = f / (n4c * 32);
  const float* inl = in + (per_l ? (size_t)l * Cin * N : 0);
  const float* Wl = W + (size_t)l * E * Cin;
  float4 acc[4];
#pragma unroll
  for (int i = 0; i < 4; i++) acc[i] = make_float4(0.f, 0.f, 0.f, 0.f);
  for (int c = 0; c < Cin; c++) {
    float4 v = *(const float4*)(inl + (size_t)c * N + n0);
    float wv[4];
#pragma unroll
    for (int i = 0; i < 4; i++) wv[i] = Wl[(e0 + i) * Cin + c];
#pragma unroll
    for (int i = 0; i < 4; i++) {
      acc[i].x += wv[i] * v.x; acc[i].y += wv[i] * v.y;
      acc[i].z += wv[i] * v.z; acc[i].w += wv[i] * v.w;
    }
  }
#pragma unroll
  for (int i = 0; i < 4; i++) {
    float bv = B[l * E + e0 + i];
    acc[i].x += bv; acc[i].y += bv; acc[i].z += bv; acc[i].w += bv;
    *(float4*)(out + ((size_t)l * E + e0 + i) * N + n0) = acc[i];
  }
}

// ---------------- qgn apply + convert to MFMA layouts --------------------------------
// blocks [0,1536): Q  -> qbf [l][h][n][16] bf16, scaled by SCALE*LOG2E (transpose)
// blocks [1536,1920): K -> kbf [l][h][k][16] bf16 (transpose)
// blocks [1920,2304): V -> vbf [l][h][d][k] bf16 (straight convert)
__global__ __launch_bounds__(256) void qkv_convert(const float* __restrict__ qn,
                                                   const float* __restrict__ kn,
                                                   const float* __restrict__ vn,
                                                   const float* __restrict__ stats,
                                                   const float* __restrict__ gw,
                                                   const float* __restrict__ gb,
                                                   __bf16* __restrict__ qbf,
                                                   __bf16* __restrict__ kbf,
                                                   __bf16* __restrict__ vbf) {
  __shared__ float T[64 * 17];
  int b = blockIdx.x, t = threadIdx.x;
  if (b < 1920) {
    const float* in; __bf16* op; int N, gbase; float extra; int idx;
    if (b < 1536) { idx = b;        N = NQ; in = qn; op = qbf; gbase = 0;  extra = SCALE * LOG2E; }
    else          { idx = b - 1536; N = NK; in = kn; op = kbf; gbase = 24; extra = 1.f; }
    int ntiles = N >> 6;
    int nt = idx % ntiles, rem = idx / ntiles;
    int h = rem & 7, l = rem >> 3;
    int n0 = nt * 64;
    int d = t >> 4, j = t & 15;
    int cidx = l * E + h * D + d;
    int g = gbase + l * 8 + h;
    float mu = stats[2 * g], rs = stats[2 * g + 1];
    float w0 = gw[cidx] * rs;
    float sc = w0 * extra;
    float sh = (gb[cidx] - mu * w0) * extra;
    float4 v = *(const float4*)(in + (size_t)cidx * N + n0 + j * 4);
    T[(j * 4 + 0) * 17 + d] = v.x * sc + sh;
    T[(j * 4 + 1) * 17 + d] = v.y * sc + sh;
    T[(j * 4 + 2) * 17 + d] = v.z * sc + sh;
    T[(j * 4 + 3) * 17 + d] = v.w * sc + sh;
    __syncthreads();
    int nl = t >> 2, dp = (t & 3) * 4;
    bf16x4 o;
#pragma unroll
    for (int ii = 0; ii < 4; ii++) o[ii] = (__bf16)T[nl * 17 + dp + ii];
    *(bf16x4*)(op + ((size_t)(l * 8 + h) * N + n0 + nl) * 16 + dp) = o;
  } else {
    int f = (b - 1920) * 256 + t;          // float4 index into vn flat [l][128][1024]
    int row = f >> 8;                      // channel-row 0..383
    int l = row >> 7, e = row & 127, h = e >> 4;
    int g = 48 + l * 8 + h;
    int cidx = l * E + e;
    float mu = stats[2 * g], rs = stats[2 * g + 1];
    float sc = gw[cidx] * rs, sh = gb[cidx] - mu * sc;
    float4 v = ((const float4*)vn)[f];
    bf16x4 o;
    o[0] = (__bf16)(v.x * sc + sh);
    o[1] = (__bf16)(v.y * sc + sh);
    o[2] = (__bf16)(v.z * sc + sh);
    o[3] = (__bf16)(v.w * sc + sh);
    ((bf16x4*)vbf)[f] = o;
  }
}

// ---------------- fused MFMA attention ------------------------------------------------
// grid (32, 8, 3), 256 threads. Wave handles 32 q. Q pre-scaled by SCALE*LOG2E.
__global__ __launch_bounds__(256) void attn_kernel(const __bf16* __restrict__ qbf,
                                                   const __bf16* __restrict__ kbf,
                                                   const __bf16* __restrict__ vbf,
                                                   float* __restrict__ ob,
                                                   float* __restrict__ wout) {
  __shared__ __bf16 Pt[4][32 * 40];      // per-wave P tile, row stride 80 B
  __shared__ float rinv_s[4][32];

  const int t = threadIdx.x;
  const int wv = t >> 6;
  const int lane = t & 63;
  const int l31 = lane & 31, half = lane >> 5, l15 = lane & 15, quad = lane >> 4;
  const int h = blockIdx.y, l = blockIdx.z;
  const int q0 = blockIdx.x * 128 + wv * 32;

  const __bf16* Qh = qbf + (size_t)(l * H + h) * NQ * D;
  const __bf16* Kh = kbf + (size_t)(l * H + h) * NK * D;
  const __bf16* Vh = vbf + (size_t)(l * H + h) * D * NK;

  const bf16x8 qfrag = *(const bf16x8*)(Qh + (size_t)(q0 + l31) * D + half * 8);

  f32x4 oa0 = {0.f, 0.f, 0.f, 0.f}, oa1 = {0.f, 0.f, 0.f, 0.f};
  float rsum[16];
#pragma unroll
  for (int r = 0; r < 16; ++r) rsum[r] = 0.f;

  __bf16* Pw = &Pt[wv][0];

  for (int c = 0; c < 32; ++c) {
    const int k0 = c * 32;
    bf16x8 kf = *(const bf16x8*)(Kh + (size_t)(k0 + l31) * D + half * 8);
    f32x16 s = {0.f,0.f,0.f,0.f,0.f,0.f,0.f,0.f,0.f,0.f,0.f,0.f,0.f,0.f,0.f,0.f};
    s = __builtin_amdgcn_mfma_f32_32x32x16_bf16(qfrag, kf, s, 0, 0, 0);
#pragma unroll
    for (int r = 0; r < 16; ++r) {
      float p = exp2_fast(fminf(s[r], CLAMP2));
      rsum[r] += p;
      int row = (r & 3) + 8 * (r >> 2) + 4 * half;
      Pw[row * 40 + l31] = (__bf16)p;
    }
    bf16x8 a0 = *(const bf16x8*)(Pw + l15 * 40 + quad * 8);
    bf16x8 a1 = *(const bf16x8*)(Pw + (16 + l15) * 40 + quad * 8);
    bf16x8 bv = *(const bf16x8*)(Vh + (size_t)l15 * NK + k0 + quad * 8);
    oa0 = __builtin_amdgcn_mfma_f32_16x16x32_bf16(a0, bv, oa0, 0, 0, 0);
    oa1 = __builtin_amdgcn_mfma_f32_16x16x32_bf16(a1, bv, oa1, 0, 0, 0);
  }

  // reduce row sums across the 32 k-lanes (within each half)
#pragma unroll
  for (int r = 0; r < 16; ++r) {
    float v = rsum[r];
    v += __shfl_xor(v, 1); v += __shfl_xor(v, 2); v += __shfl_xor(v, 4);
    v += __shfl_xor(v, 8); v += __shfl_xor(v, 16);
    rsum[r] = v;
  }
  if (l31 == 0) {
#pragma unroll
    for (int r = 0; r < 16; ++r)
      rinv_s[wv][(r & 3) + 8 * (r >> 2) + 4 * half] = 1.f / rsum[r];
  }
  // same-wave LDS producer/consumer: in-order, compiler inserts lgkmcnt waits
#pragma unroll
  for (int r = 0; r < 4; ++r) {
    int qa = quad * 4 + r;
    size_t rowbase = (size_t)(l * E + h * D + l15) * NQ + q0;
    ob[rowbase + qa] = oa0[r] * rinv_s[wv][qa];
    ob[rowbase + 16 + qa] = oa1[r] * rinv_s[wv][16 + qa];
  }

  // pass 2 (layer 2 only): recompute P, normalize, write w_att
  if (l == 2) {
    float riv[16];
#pragma unroll
    for (int r = 0; r < 16; ++r) riv[r] = 1.f / rsum[r];
    for (int c = 0; c < 32; ++c) {
      const int k0 = c * 32;
      bf16x8 kf = *(const bf16x8*)(Kh + (size_t)(k0 + l31) * D + half * 8);
      f32x16 s = {0.f,0.f,0.f,0.f,0.f,0.f,0.f,0.f,0.f,0.f,0.f,0.f,0.f,0.f,0.f,0.f};
      s = __builtin_amdgcn_mfma_f32_32x32x16_bf16(qfrag, kf, s, 0, 0, 0);
#pragma unroll
      for (int r = 0; r < 16; ++r) {
        float p = exp2_fast(fminf(s[r], CLAMP2)) * riv[r];
        int row = (r & 3) + 8 * (r >> 2) + 4 * half;
        wout[(size_t)(h * NQ + q0 + row) * NK + k0 + l31] = p;
      }
    }
  }
}

// ---------------- combine heads + residuals (fused) -----------------------------------
// out[c][n] = x + xq + (1/3) * (sum_l cb[l][c] + sum_l sum_e cw[l][c][e]*ob[l][e][n])
// grid 256 blocks x 256 threads; thread: 2 c x 4 n.
__global__ __launch_bounds__(256) void combine_kernel(const float* __restrict__ x,
                                                      const float* __restrict__ xq,
                                                      const float* __restrict__ ob,
                                                      const float* __restrict__ cw,
                                                      const float* __restrict__ cb,
                                                      float* __restrict__ out) {
  int f = blockIdx.x * 256 + threadIdx.x;
  int n0 = (f & 1023) * 4;
  int c0 = (f >> 10) * 2;
  float4 acc0 = make_float4(0.f, 0.f, 0.f, 0.f);
  float4 acc1 = make_float4(0.f, 0.f, 0.f, 0.f);
  for (int l = 0; l < LAYERS; l++) {
    const float* obl = ob + (size_t)l * E * NQ;
    const float* cwl = cw + (size_t)l * CIN * E;
#pragma unroll 4
    for (int e = 0; e < E; e++) {
      float4 ov = *(const float4*)(obl + (size_t)e * NQ + n0);
      float w0 = cwl[(c0 + 0) * E + e];
      float w1 = cwl[(c0 + 1) * E + e];
      acc0.x += w0 * ov.x; acc0.y += w0 * ov.y; acc0.z += w0 * ov.z; acc0.w += w0 * ov.w;
      acc1.x += w1 * ov.x; acc1.y += w1 * ov.y; acc1.z += w1 * ov.z; acc1.w += w1 * ov.w;
    }
  }
  const float third = 1.f / 3.f;
#pragma unroll
  for (int i = 0; i < 2; i++) {
    int c = c0 + i;
    float4 a = i ? acc1 : acc0;
    float bsum = (cb[c] + cb[CIN + c] + cb[2 * CIN + c]) * third;
    size_t off = (size_t)c * NQ + n0;
    float4 xv = *(const float4*)(x + off);
    float4 xqv = *(const float4*)(xq + off);
    float4 o;
    o.x = xv.x + xqv.x + a.x * third + bsum;
    o.y = xv.y + xqv.y + a.y * third + bsum;
    o.z = xv.z + xqv.z + a.z * third + bsum;
    o.w = xv.w + xqv.w + a.w * third + bsum;
    *(float4*)(out + off) = o;
  }
}

extern "C" void kernel_launch(void* const* d_in, const int* in_sizes, int n_in,
                              void* d_out, int out_size, void* d_ws, size_t ws_size,
                              hipStream_t stream) {
  (void)in_sizes; (void)n_in; (void)out_size;
  const float* x    = (const float*)d_in[0];
  const float* xgi  = (const float*)d_in[1];
  const float* gn1w = (const float*)d_in[4];
  const float* gn1b = (const float*)d_in[5];
  const float* gn2w = (const float*)d_in[6];
  const float* gn2b = (const float*)d_in[7];
  const float* qw   = (const float*)d_in[8];
  const float* qb   = (const float*)d_in[9];
  const float* kw   = (const float*)d_in[10];
  const float* kb   = (const float*)d_in[11];
  const float* vw   = (const float*)d_in[12];
  const float* vb   = (const float*)d_in[13];
  const float* qgnw = (const float*)d_in[14];
  const float* qgnb = (const float*)d_in[15];
  const float* cw   = (const float*)d_in[16];
  const float* cb   = (const float*)d_in[17];

  float* ws = (float*)d_ws;
  float* xq   = ws;                  // 524288   [c][n] fp32
  float* xgb  = ws + 524288;         // 786432   [l][c][n] fp32 (reused as qbf after proj)
  float* qn   = ws + 1310720;        // 1572864  [l][e][n] fp32
  float* kn   = ws + 2883584;        // 393216   (contiguous with qn for fused partials)
  float* vn   = ws + 3276800;        // 393216
  float* ob   = ws + 3670016;        // 1572864  [l][e][n] fp32
  if (ws_size < (size_t)5242880 * sizeof(float)) return;

  float* outp = (float*)d_out;       // 524288 floats final out; used as scratch before combine
  float* wout = outp + 524288;       // 33554432 floats w_att (layer 2)

  __bf16* qbf = (__bf16*)xgb;                  // 1572864 bf16 == 786432 floats (exact fit)
  __bf16* kbf = (__bf16*)outp;                 // 393216 bf16 (196608 floats)
  __bf16* vbf = (__bf16*)(outp + 196608);      // 393216 bf16
  float* part  = outp + 393216;                // up to 2304 floats
  float* statsG1  = outp + 395520;             // 16
  float* statsG2  = outp + 395536;             // 96
  float* statsQKV = outp + 395632;             // 144

  // GroupNorm(8) + ReLU on x -> xq
  gn_partial<<<256, 256, 0, stream>>>(x, part);
  gn_finalize<<<8, 64, 0, stream>>>(part, statsG1, 32, 1.f / 65536.f);
  gn_apply<<<512, 256, 0, stream>>>(x, xq, statsG1, gn1w, gn1b, 1024, 16384, 1);

  // GroupNorm(16) + ReLU on x_global -> xgb
  gn_partial<<<384, 256, 0, stream>>>(xgi, part);
  gn_finalize<<<48, 64, 0, stream>>>(part, statsG2, 8, 1.f / 16384.f);
  gn_apply<<<768, 256, 0, stream>>>(xgi, xgb, statsG2, gn2w, gn2b, 256, 4096, 1);

  // projections -> qn/kn/vn fp32
  proj_kernel<<<384, 256, 0, stream>>>(xq, qw, qb, qn, 128, 4096, 0);
  proj_kernel<<<96, 256, 0, stream>>>(xgb, kw, kb, kn, 256, 1024, 1);
  proj_kernel<<<96, 256, 0, stream>>>(xgb, vw, vb, vn, 256, 1024, 1);

  // shared GroupNorm(8) stats over q,k,v (contiguous buffers -> one partial pass)
  gn_partial<<<1152, 256, 0, stream>>>(qn, part);
  gn_finalize72<<<72, 64, 0, stream>>>(part, statsQKV);

  // normalize + convert to bf16 MFMA layouts (overwrites xgb with qbf)
  qkv_convert<<<2304, 256, 0, stream>>>(qn, kn, vn, statsQKV, qgnw, qgnb, qbf, kbf, vbf);

  // fused MFMA attention (layer 2 writes w_att)
  attn_kernel<<<dim3(32, 8, 3), 256, 0, stream>>>(qbf, kbf, vbf, ob, wout);

  // combine heads + residuals -> out (overwrites the outp scratch region last)
  combine_kernel<<<256, 256, 0, stream>>>(x, xq, ob, cw, cb, outp);
}

// Round 4
// 357.068 us; speedup vs baseline: 2.3287x; 1.2090x over previous
//
#include <hip/hip_runtime.h>
#include <math.h>

constexpr int NQ = 4096, NK = 1024, CIN = 128, CKV = 256, E = 128, H = 8, D = 16, LAYERS = 3;
constexpr float SCALE = 1.0f / 256.0f;
constexpr float CLAMP_MAX = 65503.0f;
constexpr float LOG2E = 1.44269504088896340736f;
constexpr float CLAMP2 = CLAMP_MAX * LOG2E;

typedef __bf16 bf16x8 __attribute__((ext_vector_type(8)));
typedef __bf16 bf16x4 __attribute__((ext_vector_type(4)));
typedef float f32x16 __attribute__((ext_vector_type(16)));
typedef float f32x4 __attribute__((ext_vector_type(4)));

__device__ __forceinline__ float exp2_fast(float x) {
#if __has_builtin(__builtin_amdgcn_exp2f)
  return __builtin_amdgcn_exp2f(x);
#else
  return exp2f(x);
#endif
}

// ---------------- block reduction helper (256 threads, 4 waves) ----------------
__device__ __forceinline__ void block_reduce2(float& a, float& b, float* red) {
#pragma unroll
  for (int off = 32; off > 0; off >>= 1) {
    a += __shfl_down(a, off, 64);
    b += __shfl_down(b, off, 64);
  }
  int lane = threadIdx.x & 63, wid = threadIdx.x >> 6;
  if (lane == 0) { red[wid * 2] = a; red[wid * 2 + 1] = b; }
  __syncthreads();
  if (threadIdx.x == 0) {
    float sa = 0.f, sb = 0.f;
#pragma unroll
    for (int w = 0; w < 4; w++) { sa += red[w * 2]; sb += red[w * 2 + 1]; }
    red[0] = sa; red[1] = sb;
  }
  __syncthreads();
  a = red[0]; b = red[1];
}

// ---------------- stage 1: block partial sums of x and x_global -> atomic group accums ----
// blocks [0,256): x chunks (group = b>>5, accum idx b>>5)
// blocks [256,640): x_global chunks (accum idx 8 + (b-256)>>3)
__global__ __launch_bounds__(256) void pre_partial(const float* __restrict__ x,
                                                   const float* __restrict__ xg,
                                                   float* __restrict__ acc) {
  __shared__ float red[8];
  int b = blockIdx.x, t = threadIdx.x;
  const float4* p;
  int aidx;
  if (b < 256) { p = (const float4*)x + (size_t)b * 512; aidx = b >> 5; }
  else { int i = b - 256; p = (const float4*)xg + (size_t)i * 512; aidx = 8 + (i >> 3); }
  float s = 0.f, sq = 0.f;
#pragma unroll
  for (int i = 0; i < 2; i++) {
    float4 v = p[t + i * 256];
    s += v.x + v.y + v.z + v.w;
    sq += v.x * v.x + v.y * v.y + v.z * v.z + v.w * v.w;
  }
  block_reduce2(s, sq, red);
  if (t == 0) {
    atomicAdd(&acc[aidx * 2], s);
    atomicAdd(&acc[aidx * 2 + 1], sq);
  }
}

// ---------------- stage 2: finalize gn1 (8 groups) + gn2 (48 groups) ----------------
__global__ __launch_bounds__(64) void finalize56(const float* __restrict__ acc,
                                                 float* __restrict__ stats) {
  int t = threadIdx.x;
  if (t < 56) {
    float inv = (t < 8) ? (1.f / 65536.f) : (1.f / 16384.f);
    float mu = acc[2 * t] * inv;
    float var = acc[2 * t + 1] * inv - mu * mu;
    stats[2 * t] = mu;
    stats[2 * t + 1] = rsqrtf(var + 1e-5f);
  }
}

// ---------------- stage 3: fused GN-apply + q/k/v projections + qgn stat accumulation ----
// blocks [0,384): q (x input, gn1 stats);  [384,480): k;  [480,576): v (x_global, gn2)
__global__ __launch_bounds__(256) void proj_all(const float* __restrict__ x,
                                                const float* __restrict__ xg,
                                                const float* __restrict__ stats56,
                                                const float* __restrict__ gn1w,
                                                const float* __restrict__ gn1b,
                                                const float* __restrict__ gn2w,
                                                const float* __restrict__ gn2b,
                                                const float* __restrict__ qw,
                                                const float* __restrict__ qb,
                                                const float* __restrict__ kw,
                                                const float* __restrict__ kb,
                                                const float* __restrict__ vw,
                                                const float* __restrict__ vb,
                                                float* __restrict__ qn,
                                                float* __restrict__ kn,
                                                float* __restrict__ vn,
                                                float* __restrict__ qgnAcc) {
  __shared__ float csc[256], csh[256];
  __shared__ float red[8];
  int b = blockIdx.x, t = threadIdx.x;

  const float* in; const float* W; const float* B; float* out;
  int Cin, N, l, e0, ng, gacc;
  if (b < 384) {
    int f = b * 256 + t;
    ng = f & 1023; e0 = ((f >> 10) & 31) * 4; l = f >> 15;
    in = x; Cin = CIN; N = NQ;
    W = qw + (size_t)l * E * CIN; B = qb; out = qn;
    gacc = l * 8 + (e0 >> 4);
    if (t < 128) {
      int c = t, g = c >> 4;
      float mu = stats56[2 * g], rs = stats56[2 * g + 1];
      float w0 = gn1w[c] * rs;
      csc[c] = w0; csh[c] = gn1b[c] - mu * w0;
    }
  } else {
    int part = (b < 480) ? 1 : 2;
    int idx = b - (part == 1 ? 384 : 480);
    ng = t; e0 = (idx & 31) * 4; l = idx >> 5;
    in = xg + (size_t)l * CKV * NK; Cin = CKV; N = NK;
    if (part == 1) { W = kw + (size_t)l * E * CKV; B = kb; out = kn; gacc = 24 + l * 8 + (e0 >> 4); }
    else           { W = vw + (size_t)l * E * CKV; B = vb; out = vn; gacc = 48 + l * 8 + (e0 >> 4); }
    {
      int c = t, g = 8 + l * 16 + (c >> 4);
      float mu = stats56[2 * g], rs = stats56[2 * g + 1];
      float w0 = gn2w[l * CKV + c] * rs;
      csc[c] = w0; csh[c] = gn2b[l * CKV + c] - mu * w0;
    }
  }
  __syncthreads();

  int n0 = ng * 4;
  float4 acc4[4];
#pragma unroll
  for (int i = 0; i < 4; i++) acc4[i] = make_float4(0.f, 0.f, 0.f, 0.f);
  for (int c = 0; c < Cin; c++) {
    float4 v = *(const float4*)(in + (size_t)c * N + n0);
    float sc = csc[c], sh = csh[c];
    v.x = fmaxf(v.x * sc + sh, 0.f);
    v.y = fmaxf(v.y * sc + sh, 0.f);
    v.z = fmaxf(v.z * sc + sh, 0.f);
    v.w = fmaxf(v.w * sc + sh, 0.f);
    float wv[4];
#pragma unroll
    for (int i = 0; i < 4; i++) wv[i] = W[(e0 + i) * Cin + c];
#pragma unroll
    for (int i = 0; i < 4; i++) {
      acc4[i].x += wv[i] * v.x; acc4[i].y += wv[i] * v.y;
      acc4[i].z += wv[i] * v.z; acc4[i].w += wv[i] * v.w;
    }
  }
  float s = 0.f, sq = 0.f;
#pragma unroll
  for (int i = 0; i < 4; i++) {
    float bv = B[l * E + e0 + i];
    acc4[i].x += bv; acc4[i].y += bv; acc4[i].z += bv; acc4[i].w += bv;
    *(float4*)(out + ((size_t)l * E + e0 + i) * N + n0) = acc4[i];
    s += acc4[i].x + acc4[i].y + acc4[i].z + acc4[i].w;
    sq += acc4[i].x * acc4[i].x + acc4[i].y * acc4[i].y
        + acc4[i].z * acc4[i].z + acc4[i].w * acc4[i].w;
  }
  block_reduce2(s, sq, red);
  if (t == 0) {
    atomicAdd(&qgnAcc[gacc * 2], s);
    atomicAdd(&qgnAcc[gacc * 2 + 1], sq);
  }
}

// ---------------- stage 4: finalize qgn stats (72 groups) ----------------
__global__ __launch_bounds__(128) void finalize72(const float* __restrict__ acc,
                                                  float* __restrict__ stats) {
  int t = threadIdx.x;
  if (t < 72) {
    float inv = (t < 24) ? (1.f / 65536.f) : (1.f / 16384.f);
    float mu = acc[2 * t] * inv;
    float var = acc[2 * t + 1] * inv - mu * mu;
    stats[2 * t] = mu;
    stats[2 * t + 1] = rsqrtf(var + 1e-5f);
  }
}

// ---------------- stage 5: qgn apply + convert to MFMA layouts --------------------------------
// blocks [0,1536): Q  -> qbf [l][h][n][16] bf16, scaled by SCALE*LOG2E (transpose)
// blocks [1536,1920): K -> kbf [l][h][k][16] bf16 (transpose)
// blocks [1920,2304): V -> vbf [l][h][d][k] bf16 (straight convert)
__global__ __launch_bounds__(256) void qkv_convert(const float* __restrict__ qn,
                                                   const float* __restrict__ kn,
                                                   const float* __restrict__ vn,
                                                   const float* __restrict__ stats,
                                                   const float* __restrict__ gw,
                                                   const float* __restrict__ gb,
                                                   __bf16* __restrict__ qbf,
                                                   __bf16* __restrict__ kbf,
                                                   __bf16* __restrict__ vbf) {
  __shared__ float T[64 * 17];
  int b = blockIdx.x, t = threadIdx.x;
  if (b < 1920) {
    const float* in; __bf16* op; int N, gbase; float extra; int idx;
    if (b < 1536) { idx = b;        N = NQ; in = qn; op = qbf; gbase = 0;  extra = SCALE * LOG2E; }
    else          { idx = b - 1536; N = NK; in = kn; op = kbf; gbase = 24; extra = 1.f; }
    int ntiles = N >> 6;
    int nt = idx % ntiles, rem = idx / ntiles;
    int h = rem & 7, l = rem >> 3;
    int n0 = nt * 64;
    int d = t >> 4, j = t & 15;
    int cidx = l * E + h * D + d;
    int g = gbase + l * 8 + h;
    float mu = stats[2 * g], rs = stats[2 * g + 1];
    float w0 = gw[cidx] * rs;
    float sc = w0 * extra;
    float sh = (gb[cidx] - mu * w0) * extra;
    float4 v = *(const float4*)(in + (size_t)cidx * N + n0 + j * 4);
    T[(j * 4 + 0) * 17 + d] = v.x * sc + sh;
    T[(j * 4 + 1) * 17 + d] = v.y * sc + sh;
    T[(j * 4 + 2) * 17 + d] = v.z * sc + sh;
    T[(j * 4 + 3) * 17 + d] = v.w * sc + sh;
    __syncthreads();
    int nl = t >> 2, dp = (t & 3) * 4;
    bf16x4 o;
#pragma unroll
    for (int ii = 0; ii < 4; ii++) o[ii] = (__bf16)T[nl * 17 + dp + ii];
    *(bf16x4*)(op + ((size_t)(l * 8 + h) * N + n0 + nl) * 16 + dp) = o;
  } else {
    int f = (b - 1920) * 256 + t;          // float4 index into vn flat [l][128][1024]
    int row = f >> 8;                      // channel-row 0..383
    int l = row >> 7, e = row & 127, h = e >> 4;
    int g = 48 + l * 8 + h;
    int cidx = l * E + e;
    float mu = stats[2 * g], rs = stats[2 * g + 1];
    float sc = gw[cidx] * rs, sh = gb[cidx] - mu * sc;
    float4 v = ((const float4*)vn)[f];
    bf16x4 o;
    o[0] = (__bf16)(v.x * sc + sh);
    o[1] = (__bf16)(v.y * sc + sh);
    o[2] = (__bf16)(v.z * sc + sh);
    o[3] = (__bf16)(v.w * sc + sh);
    ((bf16x4*)vbf)[f] = o;
  }
}

// ---------------- stage 6: fused MFMA attention ---------------------------------------
// grid (32, 8, 3), 256 threads. Wave handles 32 q. Q pre-scaled by SCALE*LOG2E.
__global__ __launch_bounds__(256) void attn_kernel(const __bf16* __restrict__ qbf,
                                                   const __bf16* __restrict__ kbf,
                                                   const __bf16* __restrict__ vbf,
                                                   float* __restrict__ ob,
                                                   float* __restrict__ wout) {
  __shared__ __bf16 Pt[4][32 * 40];      // per-wave P tile, row stride 80 B (2560 B/wave)
  __shared__ float rinv_s[4][32];

  const int t = threadIdx.x;
  const int wv = t >> 6;
  const int lane = t & 63;
  const int l31 = lane & 31, half = lane >> 5, l15 = lane & 15, quad = lane >> 4;
  const int h = blockIdx.y, l = blockIdx.z;
  const int q0 = blockIdx.x * 128 + wv * 32;

  const __bf16* Qh = qbf + (size_t)(l * H + h) * NQ * D;
  const __bf16* Kh = kbf + (size_t)(l * H + h) * NK * D;
  const __bf16* Vh = vbf + (size_t)(l * H + h) * D * NK;

  const bf16x8 qfrag = *(const bf16x8*)(Qh + (size_t)(q0 + l31) * D + half * 8);

  f32x4 oa0 = {0.f, 0.f, 0.f, 0.f}, oa1 = {0.f, 0.f, 0.f, 0.f};
  float rsum[16];
#pragma unroll
  for (int r = 0; r < 16; ++r) rsum[r] = 0.f;

  __bf16* Pw = &Pt[wv][0];

  for (int c = 0; c < 32; ++c) {
    const int k0 = c * 32;
    bf16x8 kf = *(const bf16x8*)(Kh + (size_t)(k0 + l31) * D + half * 8);
    f32x16 s = {0.f,0.f,0.f,0.f,0.f,0.f,0.f,0.f,0.f,0.f,0.f,0.f,0.f,0.f,0.f,0.f};
    s = __builtin_amdgcn_mfma_f32_32x32x16_bf16(qfrag, kf, s, 0, 0, 0);
#pragma unroll
    for (int r = 0; r < 16; ++r) {
      float p = exp2_fast(fminf(s[r], CLAMP2));
      rsum[r] += p;
      int row = (r & 3) + 8 * (r >> 2) + 4 * half;
      Pw[row * 40 + l31] = (__bf16)p;
    }
    bf16x8 a0 = *(const bf16x8*)(Pw + l15 * 40 + quad * 8);
    bf16x8 a1 = *(const bf16x8*)(Pw + (16 + l15) * 40 + quad * 8);
    bf16x8 bv = *(const bf16x8*)(Vh + (size_t)l15 * NK + k0 + quad * 8);
    oa0 = __builtin_amdgcn_mfma_f32_16x16x32_bf16(a0, bv, oa0, 0, 0, 0);
    oa1 = __builtin_amdgcn_mfma_f32_16x16x32_bf16(a1, bv, oa1, 0, 0, 0);
  }

  // reduce row sums across the 32 k-lanes (within each half)
#pragma unroll
  for (int r = 0; r < 16; ++r) {
    float v = rsum[r];
    v += __shfl_xor(v, 1); v += __shfl_xor(v, 2); v += __shfl_xor(v, 4);
    v += __shfl_xor(v, 8); v += __shfl_xor(v, 16);
    rsum[r] = v;
  }
  if (l31 == 0) {
#pragma unroll
    for (int r = 0; r < 16; ++r)
      rinv_s[wv][(r & 3) + 8 * (r >> 2) + 4 * half] = 1.f / rsum[r];
  }

  // ---- coalesced O store: transpose through per-wave LDS tile (aliases Pt[wv]) ----
  float* Ow = (float*)Pw;                       // 16 rows x stride 36 floats (2304 B < 2560 B)
#pragma unroll
  for (int r = 0; r < 4; ++r) {
    int qa = quad * 4 + r;
    Ow[l15 * 36 + qa] = oa0[r] * rinv_s[wv][qa];
    Ow[l15 * 36 + 16 + qa] = oa1[r] * rinv_s[wv][16 + qa];
  }
  {
    int dd = lane >> 2, j = (lane & 3) * 8;
    float4 u0 = *(const float4*)(Ow + dd * 36 + j);
    float4 u1 = *(const float4*)(Ow + dd * 36 + j + 4);
    size_t rb = (size_t)(l * E + h * D + dd) * NQ + q0 + j;
    *(float4*)(ob + rb) = u0;
    *(float4*)(ob + rb + 4) = u1;
  }

  // pass 2 (layer 2 only): recompute P, normalize, write w_att
  if (l == 2) {
    float riv[16];
#pragma unroll
    for (int r = 0; r < 16; ++r) riv[r] = 1.f / rsum[r];
    for (int c = 0; c < 32; ++c) {
      const int k0 = c * 32;
      bf16x8 kf = *(const bf16x8*)(Kh + (size_t)(k0 + l31) * D + half * 8);
      f32x16 s = {0.f,0.f,0.f,0.f,0.f,0.f,0.f,0.f,0.f,0.f,0.f,0.f,0.f,0.f,0.f,0.f};
      s = __builtin_amdgcn_mfma_f32_32x32x16_bf16(qfrag, kf, s, 0, 0, 0);
#pragma unroll
      for (int r = 0; r < 16; ++r) {
        float p = exp2_fast(fminf(s[r], CLAMP2)) * riv[r];
        int row = (r & 3) + 8 * (r >> 2) + 4 * half;
        wout[(size_t)(h * NQ + q0 + row) * NK + k0 + l31] = p;
      }
    }
  }
}

// ---------------- stage 7: combine heads + residuals (xq recomputed inline) -------------
__global__ __launch_bounds__(256) void combine_kernel(const float* __restrict__ x,
                                                      const float* __restrict__ stats56,
                                                      const float* __restrict__ gn1w,
                                                      const float* __restrict__ gn1b,
                                                      const float* __restrict__ ob,
                                                      const float* __restrict__ cw,
                                                      const float* __restrict__ cb,
                                                      float* __restrict__ out) {
  int f = blockIdx.x * 256 + threadIdx.x;
  int n0 = (f & 1023) * 4;
  int c0 = (f >> 10) * 2;
  float4 acc0 = make_float4(0.f, 0.f, 0.f, 0.f);
  float4 acc1 = make_float4(0.f, 0.f, 0.f, 0.f);
  for (int l = 0; l < LAYERS; l++) {
    const float* obl = ob + (size_t)l * E * NQ;
    const float* cwl = cw + (size_t)l * CIN * E;
#pragma unroll 4
    for (int e = 0; e < E; e++) {
      float4 ov = *(const float4*)(obl + (size_t)e * NQ + n0);
      float w0 = cwl[(c0 + 0) * E + e];
      float w1 = cwl[(c0 + 1) * E + e];
      acc0.x += w0 * ov.x; acc0.y += w0 * ov.y; acc0.z += w0 * ov.z; acc0.w += w0 * ov.w;
      acc1.x += w1 * ov.x; acc1.y += w1 * ov.y; acc1.z += w1 * ov.z; acc1.w += w1 * ov.w;
    }
  }
  const float third = 1.f / 3.f;
#pragma unroll
  for (int i = 0; i < 2; i++) {
    int c = c0 + i;
    float4 a = i ? acc1 : acc0;
    float bsum = (cb[c] + cb[CIN + c] + cb[2 * CIN + c]) * third;
    int g = c >> 4;
    float mu = stats56[2 * g], rs = stats56[2 * g + 1];
    float sc = gn1w[c] * rs, sh = gn1b[c] - mu * sc;
    size_t off = (size_t)c * NQ + n0;
    float4 xv = *(const float4*)(x + off);
    float4 xqv;
    xqv.x = fmaxf(xv.x * sc + sh, 0.f);
    xqv.y = fmaxf(xv.y * sc + sh, 0.f);
    xqv.z = fmaxf(xv.z * sc + sh, 0.f);
    xqv.w = fmaxf(xv.w * sc + sh, 0.f);
    float4 o;
    o.x = xv.x + xqv.x + a.x * third + bsum;
    o.y = xv.y + xqv.y + a.y * third + bsum;
    o.z = xv.z + xqv.z + a.z * third + bsum;
    o.w = xv.w + xqv.w + a.w * third + bsum;
    *(float4*)(out + off) = o;
  }
}

extern "C" void kernel_launch(void* const* d_in, const int* in_sizes, int n_in,
                              void* d_out, int out_size, void* d_ws, size_t ws_size,
                              hipStream_t stream) {
  (void)in_sizes; (void)n_in; (void)out_size;
  const float* x    = (const float*)d_in[0];
  const float* xgi  = (const float*)d_in[1];
  const float* gn1w = (const float*)d_in[4];
  const float* gn1b = (const float*)d_in[5];
  const float* gn2w = (const float*)d_in[6];
  const float* gn2b = (const float*)d_in[7];
  const float* qw   = (const float*)d_in[8];
  const float* qb   = (const float*)d_in[9];
  const float* kw   = (const float*)d_in[10];
  const float* kb   = (const float*)d_in[11];
  const float* vw   = (const float*)d_in[12];
  const float* vb   = (const float*)d_in[13];
  const float* qgnw = (const float*)d_in[14];
  const float* qgnb = (const float*)d_in[15];
  const float* cw   = (const float*)d_in[16];
  const float* cb   = (const float*)d_in[17];

  float* ws = (float*)d_ws;
  float* qn  = ws;                       // 1572864  [l][e][n] fp32
  float* kn  = ws + 1572864;             // 393216   [l][e][k] fp32
  float* vn  = ws + 1966080;             // 393216   [l][e][k] fp32
  float* ob  = ws + 2359296;             // 1572864  [l][e][n] fp32
  __bf16* qbf = (__bf16*)(ws + 3932160); // 1572864 bf16 (786432 f)
  __bf16* kbf = (__bf16*)(ws + 4718592); // 393216 bf16 (196608 f)
  __bf16* vbf = (__bf16*)(ws + 4915200); // 393216 bf16 (196608 f)
  float* accAll   = ws + 5111808;        // 256: [0,112) gn1/gn2, [112,256) qgn
  float* stats56  = ws + 5112064;        // 112
  float* statsQKV = ws + 5112176;        // 144
  if (ws_size < (size_t)5112320 * sizeof(float)) return;

  float* qgnAcc = accAll + 112;
  float* outp = (float*)d_out;           // 524288 floats final out
  float* wout = outp + 524288;           // 33554432 floats w_att (layer 2)

  // 0) zero the atomic accumulators (poisoned 0xAA by harness)
  hipMemsetAsync(accAll, 0, 256 * sizeof(float), stream);

  // 1) block partials for gn1(x) + gn2(x_global), atomics into group accums
  pre_partial<<<640, 256, 0, stream>>>(x, xgi, accAll);

  // 2) finalize gn1+gn2 stats
  finalize56<<<1, 64, 0, stream>>>(accAll, stats56);

  // 3) fused GN-apply + q/k/v projections + qgn stat accumulation
  proj_all<<<576, 256, 0, stream>>>(x, xgi, stats56, gn1w, gn1b, gn2w, gn2b,
                                    qw, qb, kw, kb, vw, vb, qn, kn, vn, qgnAcc);

  // 4) finalize qgn stats (72 groups)
  finalize72<<<1, 128, 0, stream>>>(qgnAcc, statsQKV);

  // 5) qgn apply + convert to bf16 MFMA layouts
  qkv_convert<<<2304, 256, 0, stream>>>(qn, kn, vn, statsQKV, qgnw, qgnb, qbf, kbf, vbf);

  // 6) fused MFMA attention (layer 2 writes w_att)
  attn_kernel<<<dim3(32, 8, 3), 256, 0, stream>>>(qbf, kbf, vbf, ob, wout);

  // 7) combine heads + residuals -> out
  combine_kernel<<<256, 256, 0, stream>>>(x, stats56, gn1w, gn1b, ob, cw, cb, outp);
}

// Round 5
// 309.746 us; speedup vs baseline: 2.6845x; 1.1528x over previous
//
#include <hip/hip_runtime.h>
#include <math.h>

constexpr int NQ = 4096, NK = 1024, CIN = 128, CKV = 256, E = 128, H = 8, D = 16, LAYERS = 3;
constexpr float SCALE = 1.0f / 256.0f;
constexpr float CLAMP_MAX = 65503.0f;
constexpr float LOG2E = 1.44269504088896340736f;
constexpr float CLAMP2 = CLAMP_MAX * LOG2E;

typedef __bf16 bf16x8 __attribute__((ext_vector_type(8)));
typedef __bf16 bf16x4 __attribute__((ext_vector_type(4)));
typedef float f32x16 __attribute__((ext_vector_type(16)));
typedef float f32x4 __attribute__((ext_vector_type(4)));

__device__ __forceinline__ float exp2_fast(float x) {
#if __has_builtin(__builtin_amdgcn_exp2f)
  return __builtin_amdgcn_exp2f(x);
#else
  return exp2f(x);
#endif
}

// ---------------- block reduction helper (256 threads, 4 waves) ----------------
__device__ __forceinline__ void block_reduce2(float& a, float& b, float* red) {
#pragma unroll
  for (int off = 32; off > 0; off >>= 1) {
    a += __shfl_down(a, off, 64);
    b += __shfl_down(b, off, 64);
  }
  int lane = threadIdx.x & 63, wid = threadIdx.x >> 6;
  if (lane == 0) { red[wid * 2] = a; red[wid * 2 + 1] = b; }
  __syncthreads();
  if (threadIdx.x == 0) {
    float sa = 0.f, sb = 0.f;
#pragma unroll
    for (int w = 0; w < 4; w++) { sa += red[w * 2]; sb += red[w * 2 + 1]; }
    red[0] = sa; red[1] = sb;
  }
  __syncthreads();
  a = red[0]; b = red[1];
}

// ---------------- stage 1: block partial sums of x and x_global -> atomic group accums ----
__global__ __launch_bounds__(256) void pre_partial(const float* __restrict__ x,
                                                   const float* __restrict__ xg,
                                                   float* __restrict__ acc) {
  __shared__ float red[8];
  int b = blockIdx.x, t = threadIdx.x;
  const float4* p;
  int aidx;
  if (b < 256) { p = (const float4*)x + (size_t)b * 512; aidx = b >> 5; }
  else { int i = b - 256; p = (const float4*)xg + (size_t)i * 512; aidx = 8 + (i >> 3); }
  float s = 0.f, sq = 0.f;
#pragma unroll
  for (int i = 0; i < 2; i++) {
    float4 v = p[t + i * 256];
    s += v.x + v.y + v.z + v.w;
    sq += v.x * v.x + v.y * v.y + v.z * v.z + v.w * v.w;
  }
  block_reduce2(s, sq, red);
  if (t == 0) {
    atomicAdd(&acc[aidx * 2], s);
    atomicAdd(&acc[aidx * 2 + 1], sq);
  }
}

// ---------------- stage 2: GN-apply+ReLU -> bf16 transposed [n][c]; weight bf16 casts ----
// blocks [0,128): x -> xq_t [4096][128]
// blocks [128,320): x_global -> xg_t [l][1024][256] (two 128-c halves per (l,n-tile))
// blocks [320,440): qw/kw/vw fp32 -> bf16 flat cast
__global__ __launch_bounds__(256) void stage_a(const float* __restrict__ x,
                                               const float* __restrict__ xg,
                                               const float* __restrict__ acc,
                                               const float* __restrict__ gn1w,
                                               const float* __restrict__ gn1b,
                                               const float* __restrict__ gn2w,
                                               const float* __restrict__ gn2b,
                                               const float* __restrict__ qw,
                                               const float* __restrict__ kw,
                                               const float* __restrict__ vw,
                                               __bf16* __restrict__ xq_t,
                                               __bf16* __restrict__ xg_t,
                                               __bf16* __restrict__ qwb,
                                               __bf16* __restrict__ kwb,
                                               __bf16* __restrict__ vwb) {
  int b = blockIdx.x, t = threadIdx.x;
  if (b >= 320) {
    int i = b - 320;
    const float* src; __bf16* dst; int off;
    if (i < 24)      { src = qw; dst = qwb; off = i * 2048; }
    else if (i < 72) { src = kw; dst = kwb; off = (i - 24) * 2048; }
    else             { src = vw; dst = vwb; off = (i - 72) * 2048; }
    int base = off + t * 8;
    float4 a = *(const float4*)(src + base);
    float4 c = *(const float4*)(src + base + 4);
    bf16x8 o = { (__bf16)a.x, (__bf16)a.y, (__bf16)a.z, (__bf16)a.w,
                 (__bf16)c.x, (__bf16)c.y, (__bf16)c.z, (__bf16)c.w };
    *(bf16x8*)(dst + base) = o;
    return;
  }
  __shared__ float T[128 * 36];
  const float* in; __bf16* out; int N, Cout, ccbase, n0, gbase;
  const float* gw; const float* gb; float inv;
  if (b < 128) {
    in = x; N = NQ; out = xq_t; Cout = 128; ccbase = 0; n0 = b * 32;
    gw = gn1w; gb = gn1b; gbase = 0; inv = 1.f / 65536.f;
  } else {
    int i = b - 128; int l = i / 64; int r = i % 64; int ch = r >> 5;
    n0 = (r & 31) * 32;
    in = xg + ((size_t)l * 256 + ch * 128) * 1024; N = NK;
    out = xg_t + (size_t)l * 1024 * 256; Cout = 256; ccbase = ch * 128;
    gw = gn2w + l * 256 + ch * 128; gb = gn2b + l * 256 + ch * 128;
    gbase = 8 + l * 16 + ch * 8; inv = 1.f / 16384.f;
  }
  int nq = t & 7, cbase = t >> 3;
#pragma unroll
  for (int i = 0; i < 4; i++) {
    int c = cbase + 32 * i;
    int g = gbase + (c >> 4);
    float mu = acc[2 * g] * inv;
    float rs = rsqrtf(acc[2 * g + 1] * inv - mu * mu + 1e-5f);
    float sc = gw[c] * rs, sh = gb[c] - mu * sc;
    float4 v = *(const float4*)(in + (size_t)c * N + n0 + nq * 4);
    float4 o;
    o.x = fmaxf(v.x * sc + sh, 0.f);
    o.y = fmaxf(v.y * sc + sh, 0.f);
    o.z = fmaxf(v.z * sc + sh, 0.f);
    o.w = fmaxf(v.w * sc + sh, 0.f);
    *(float4*)(T + c * 36 + nq * 4) = o;
  }
  __syncthreads();
  int n = t >> 3, c0 = (t & 7) * 16;
  bf16x8 o1, o2;
#pragma unroll
  for (int j = 0; j < 8; j++) {
    o1[j] = (__bf16)T[(c0 + j) * 36 + n];
    o2[j] = (__bf16)T[(c0 + 8 + j) * 36 + n];
  }
  __bf16* op = out + (size_t)(n0 + n) * Cout + ccbase + c0;
  *(bf16x8*)op = o1;
  *(bf16x8*)(op + 8) = o2;
}

// ---------------- stage 3: MFMA projections + bias + qgn stats + layout stores ----------
template <int KSTEPS>
__device__ __forceinline__ void gemm_tile(const __bf16* __restrict__ A,
                                          const __bf16* __restrict__ Bm,
                                          int stride, f32x16& acc, int l31, int half) {
#pragma unroll
  for (int ks = 0; ks < KSTEPS; ks++) {
    bf16x8 af = *(const bf16x8*)(A + (size_t)l31 * stride + ks * 16 + half * 8);
    bf16x8 bf = *(const bf16x8*)(Bm + (size_t)l31 * stride + ks * 16 + half * 8);
    acc = __builtin_amdgcn_mfma_f32_32x32x16_bf16(af, bf, acc, 0, 0, 0);
  }
}

__global__ __launch_bounds__(256) void proj_mfma(const __bf16* __restrict__ xq_t,
                                                 const __bf16* __restrict__ xg_t,
                                                 const __bf16* __restrict__ qwb,
                                                 const __bf16* __restrict__ kwb,
                                                 const __bf16* __restrict__ vwb,
                                                 const float* __restrict__ qb,
                                                 const float* __restrict__ kb,
                                                 const float* __restrict__ vb,
                                                 __bf16* __restrict__ q_raw,
                                                 __bf16* __restrict__ k_raw,
                                                 __bf16* __restrict__ v_raw,
                                                 float* __restrict__ qgnAcc) {
  int t = threadIdx.x;
  int w = blockIdx.x * 4 + (t >> 6);
  int lane = t & 63, l31 = lane & 31, half = lane >> 5;
  f32x16 acc = {0.f,0.f,0.f,0.f,0.f,0.f,0.f,0.f,0.f,0.f,0.f,0.f,0.f,0.f,0.f,0.f};
  int mat, l, e0, n0, N;
  const __bf16* A; const __bf16* Bm; const float* bias;
  if (w < 1536) {
    mat = 0; l = w >> 9; int r = w & 511; e0 = (r & 3) * 32; n0 = (r >> 2) * 32;
    N = NQ; A = qwb + (size_t)l * 128 * 128; Bm = xq_t; bias = qb + l * 128;
  } else if (w < 1920) {
    mat = 1; int idx = w - 1536; l = idx >> 7; int r = idx & 127;
    e0 = (r & 3) * 32; n0 = (r >> 2) * 32;
    N = NK; A = kwb + (size_t)l * 128 * 256; Bm = xg_t + (size_t)l * 1024 * 256;
    bias = kb + l * 128;
  } else {
    mat = 2; int idx = w - 1920; l = idx >> 7; int r = idx & 127;
    e0 = (r & 3) * 32; n0 = (r >> 2) * 32;
    N = NK; A = vwb + (size_t)l * 128 * 256; Bm = xg_t + (size_t)l * 1024 * 256;
    bias = vb + l * 128;
  }
  if (mat == 0) {
    gemm_tile<8>(A + (size_t)e0 * 128, Bm + (size_t)n0 * 128, 128, acc, l31, half);
  } else {
    gemm_tile<16>(A + (size_t)e0 * 256, Bm + (size_t)n0 * 256, 256, acc, l31, half);
  }

  float vals[16];
  float s0 = 0.f, sq0 = 0.f, s1 = 0.f, sq1 = 0.f;
#pragma unroll
  for (int r = 0; r < 16; r++) {
    int row = (r & 3) + 8 * (r >> 2) + 4 * half;
    float v = acc[r] + bias[e0 + row];
    vals[r] = v;
    if (r < 8) { s0 += v; sq0 += v * v; } else { s1 += v; sq1 += v * v; }
  }
#pragma unroll
  for (int off = 1; off < 64; off <<= 1) {
    s0 += __shfl_xor(s0, off); sq0 += __shfl_xor(sq0, off);
    s1 += __shfl_xor(s1, off); sq1 += __shfl_xor(sq1, off);
  }
  int gbase = (mat == 0 ? 0 : (mat == 1 ? 24 : 48)) + l * 8 + (e0 >> 4);
  if (lane == 0) {
    atomicAdd(&qgnAcc[gbase * 2], s0);
    atomicAdd(&qgnAcc[gbase * 2 + 1], sq0);
    atomicAdd(&qgnAcc[(gbase + 1) * 2], s1);
    atomicAdd(&qgnAcc[(gbase + 1) * 2 + 1], sq1);
  }
  if (mat < 2) {
    __bf16* out = (mat == 0 ? q_raw : k_raw);
#pragma unroll
    for (int qd = 0; qd < 4; qd++) {
      int h = (e0 >> 4) + (qd >> 1);
      int d0 = 4 * half + 8 * (qd & 1);
      bf16x4 o;
#pragma unroll
      for (int j = 0; j < 4; j++) o[j] = (__bf16)vals[qd * 4 + j];
      *(bf16x4*)(out + ((size_t)(l * 8 + h) * N + n0 + l31) * 16 + d0) = o;
    }
  } else {
#pragma unroll
    for (int r = 0; r < 16; r++) {
      int row = (r & 3) + 8 * (r >> 2) + 4 * half;
      int h = (e0 >> 4) + (row >> 4);
      v_raw[((size_t)(l * 8 + h) * 16 + (row & 15)) * NK + n0 + l31] = (__bf16)vals[r];
    }
  }
}

// ---------------- stage 4: in-place qgn affine on bf16 q/k/v (Q folds SCALE*LOG2E) -------
__global__ __launch_bounds__(256) void qkv_affine(__bf16* __restrict__ q_raw,
                                                  __bf16* __restrict__ k_raw,
                                                  __bf16* __restrict__ v_raw,
                                                  const float* __restrict__ acc,
                                                  const float* __restrict__ gw,
                                                  const float* __restrict__ gb) {
  int b = blockIdx.x, t = threadIdx.x;
  if (b < 768) {
    int v8 = b * 256 + t;
    int d0 = (v8 & 1) * 8;
    int lh = (v8 >> 1) >> 12;
    int l = lh >> 3, h = lh & 7;
    int g = l * 8 + h;
    const float inv = 1.f / 65536.f;
    float mu = acc[2 * g] * inv;
    float rs = rsqrtf(acc[2 * g + 1] * inv - mu * mu + 1e-5f);
    const float EX = SCALE * LOG2E;
    bf16x8 vv = *(bf16x8*)(q_raw + (size_t)v8 * 8);
    bf16x8 o;
#pragma unroll
    for (int j = 0; j < 8; j++) {
      int cidx = l * 128 + h * 16 + d0 + j;
      float w0 = gw[cidx] * rs;
      o[j] = (__bf16)(((float)vv[j] * w0 + (gb[cidx] - mu * w0)) * EX);
    }
    *(bf16x8*)(q_raw + (size_t)v8 * 8) = o;
  } else if (b < 960) {
    int v8 = (b - 768) * 256 + t;
    int d0 = (v8 & 1) * 8;
    int lh = (v8 >> 1) >> 10;
    int l = lh >> 3, h = lh & 7;
    int g = 24 + l * 8 + h;
    const float inv = 1.f / 16384.f;
    float mu = acc[2 * g] * inv;
    float rs = rsqrtf(acc[2 * g + 1] * inv - mu * mu + 1e-5f);
    bf16x8 vv = *(bf16x8*)(k_raw + (size_t)v8 * 8);
    bf16x8 o;
#pragma unroll
    for (int j = 0; j < 8; j++) {
      int cidx = l * 128 + h * 16 + d0 + j;
      float w0 = gw[cidx] * rs;
      o[j] = (__bf16)((float)vv[j] * w0 + (gb[cidx] - mu * w0));
    }
    *(bf16x8*)(k_raw + (size_t)v8 * 8) = o;
  } else {
    int v8 = (b - 960) * 256 + t;
    int rest = v8 >> 7;
    int d = rest & 15, lh = rest >> 4;
    int l = lh >> 3, h = lh & 7;
    int g = 48 + l * 8 + h;
    const float inv = 1.f / 16384.f;
    float mu = acc[2 * g] * inv;
    float rs = rsqrtf(acc[2 * g + 1] * inv - mu * mu + 1e-5f);
    int cidx = l * 128 + h * 16 + d;
    float w0 = gw[cidx] * rs;
    float sh = gb[cidx] - mu * w0;
    bf16x8 vv = *(bf16x8*)(v_raw + (size_t)v8 * 8);
    bf16x8 o;
#pragma unroll
    for (int j = 0; j < 8; j++) o[j] = (__bf16)((float)vv[j] * w0 + sh);
    *(bf16x8*)(v_raw + (size_t)v8 * 8) = o;
  }
}

// ---------------- stage 5: fused MFMA attention ---------------------------------------
__global__ __launch_bounds__(256) void attn_kernel(const __bf16* __restrict__ qbf,
                                                   const __bf16* __restrict__ kbf,
                                                   const __bf16* __restrict__ vbf,
                                                   float* __restrict__ ob,
                                                   float* __restrict__ wout) {
  __shared__ __bf16 Pt[4][32 * 40];
  __shared__ float rinv_s[4][32];

  const int t = threadIdx.x;
  const int wv = t >> 6;
  const int lane = t & 63;
  const int l31 = lane & 31, half = lane >> 5, l15 = lane & 15, quad = lane >> 4;
  const int h = blockIdx.y, l = blockIdx.z;
  const int q0 = blockIdx.x * 128 + wv * 32;

  const __bf16* Qh = qbf + (size_t)(l * H + h) * NQ * D;
  const __bf16* Kh = kbf + (size_t)(l * H + h) * NK * D;
  const __bf16* Vh = vbf + (size_t)(l * H + h) * D * NK;

  const bf16x8 qfrag = *(const bf16x8*)(Qh + (size_t)(q0 + l31) * D + half * 8);

  f32x4 oa0 = {0.f, 0.f, 0.f, 0.f}, oa1 = {0.f, 0.f, 0.f, 0.f};
  float rsum[16];
#pragma unroll
  for (int r = 0; r < 16; ++r) rsum[r] = 0.f;

  __bf16* Pw = &Pt[wv][0];

  for (int c = 0; c < 32; ++c) {
    const int k0 = c * 32;
    bf16x8 kf = *(const bf16x8*)(Kh + (size_t)(k0 + l31) * D + half * 8);
    f32x16 s = {0.f,0.f,0.f,0.f,0.f,0.f,0.f,0.f,0.f,0.f,0.f,0.f,0.f,0.f,0.f,0.f};
    s = __builtin_amdgcn_mfma_f32_32x32x16_bf16(qfrag, kf, s, 0, 0, 0);
#pragma unroll
    for (int r = 0; r < 16; ++r) {
      float p = exp2_fast(fminf(s[r], CLAMP2));
      rsum[r] += p;
      int row = (r & 3) + 8 * (r >> 2) + 4 * half;
      Pw[row * 40 + l31] = (__bf16)p;
    }
    bf16x8 a0 = *(const bf16x8*)(Pw + l15 * 40 + quad * 8);
    bf16x8 a1 = *(const bf16x8*)(Pw + (16 + l15) * 40 + quad * 8);
    bf16x8 bv = *(const bf16x8*)(Vh + (size_t)l15 * NK + k0 + quad * 8);
    oa0 = __builtin_amdgcn_mfma_f32_16x16x32_bf16(a0, bv, oa0, 0, 0, 0);
    oa1 = __builtin_amdgcn_mfma_f32_16x16x32_bf16(a1, bv, oa1, 0, 0, 0);
  }

#pragma unroll
  for (int r = 0; r < 16; ++r) {
    float v = rsum[r];
    v += __shfl_xor(v, 1); v += __shfl_xor(v, 2); v += __shfl_xor(v, 4);
    v += __shfl_xor(v, 8); v += __shfl_xor(v, 16);
    rsum[r] = v;
  }
  if (l31 == 0) {
#pragma unroll
    for (int r = 0; r < 16; ++r)
      rinv_s[wv][(r & 3) + 8 * (r >> 2) + 4 * half] = 1.f / rsum[r];
  }

  float* Ow = (float*)Pw;
#pragma unroll
  for (int r = 0; r < 4; ++r) {
    int qa = quad * 4 + r;
    Ow[l15 * 36 + qa] = oa0[r] * rinv_s[wv][qa];
    Ow[l15 * 36 + 16 + qa] = oa1[r] * rinv_s[wv][16 + qa];
  }
  {
    int dd = lane >> 2, j = (lane & 3) * 8;
    float4 u0 = *(const float4*)(Ow + dd * 36 + j);
    float4 u1 = *(const float4*)(Ow + dd * 36 + j + 4);
    size_t rb = (size_t)(l * E + h * D + dd) * NQ + q0 + j;
    *(float4*)(ob + rb) = u0;
    *(float4*)(ob + rb + 4) = u1;
  }

  if (l == 2) {
    float riv[16];
#pragma unroll
    for (int r = 0; r < 16; ++r) riv[r] = 1.f / rsum[r];
    for (int c = 0; c < 32; ++c) {
      const int k0 = c * 32;
      bf16x8 kf = *(const bf16x8*)(Kh + (size_t)(k0 + l31) * D + half * 8);
      f32x16 s = {0.f,0.f,0.f,0.f,0.f,0.f,0.f,0.f,0.f,0.f,0.f,0.f,0.f,0.f,0.f,0.f};
      s = __builtin_amdgcn_mfma_f32_32x32x16_bf16(qfrag, kf, s, 0, 0, 0);
#pragma unroll
      for (int r = 0; r < 16; ++r) {
        float p = exp2_fast(fminf(s[r], CLAMP2)) * riv[r];
        int row = (r & 3) + 8 * (r >> 2) + 4 * half;
        wout[(size_t)(h * NQ + q0 + row) * NK + k0 + l31] = p;
      }
    }
  }
}

// ---------------- stage 6: combine heads + residuals (stats inline) ---------------------
__global__ __launch_bounds__(256) void combine_kernel(const float* __restrict__ x,
                                                      const float* __restrict__ acc,
                                                      const float* __restrict__ gn1w,
                                                      const float* __restrict__ gn1b,
                                                      const float* __restrict__ ob,
                                                      const float* __restrict__ cw,
                                                      const float* __restrict__ cb,
                                                      float* __restrict__ out) {
  int f = blockIdx.x * 256 + threadIdx.x;
  int n0 = (f & 1023) * 4;
  int c0 = (f >> 10) * 2;
  float4 acc0 = make_float4(0.f, 0.f, 0.f, 0.f);
  float4 acc1 = make_float4(0.f, 0.f, 0.f, 0.f);
  for (int l = 0; l < LAYERS; l++) {
    const float* obl = ob + (size_t)l * E * NQ;
    const float* cwl = cw + (size_t)l * CIN * E;
#pragma unroll 4
    for (int e = 0; e < E; e++) {
      float4 ov = *(const float4*)(obl + (size_t)e * NQ + n0);
      float w0 = cwl[(c0 + 0) * E + e];
      float w1 = cwl[(c0 + 1) * E + e];
      acc0.x += w0 * ov.x; acc0.y += w0 * ov.y; acc0.z += w0 * ov.z; acc0.w += w0 * ov.w;
      acc1.x += w1 * ov.x; acc1.y += w1 * ov.y; acc1.z += w1 * ov.z; acc1.w += w1 * ov.w;
    }
  }
  const float third = 1.f / 3.f;
#pragma unroll
  for (int i = 0; i < 2; i++) {
    int c = c0 + i;
    float4 a = i ? acc1 : acc0;
    float bsum = (cb[c] + cb[CIN + c] + cb[2 * CIN + c]) * third;
    int g = c >> 4;
    const float inv = 1.f / 65536.f;
    float mu = acc[2 * g] * inv;
    float rs = rsqrtf(acc[2 * g + 1] * inv - mu * mu + 1e-5f);
    float sc = gn1w[c] * rs, sh = gn1b[c] - mu * sc;
    size_t off = (size_t)c * NQ + n0;
    float4 xv = *(const float4*)(x + off);
    float4 xqv;
    xqv.x = fmaxf(xv.x * sc + sh, 0.f);
    xqv.y = fmaxf(xv.y * sc + sh, 0.f);
    xqv.z = fmaxf(xv.z * sc + sh, 0.f);
    xqv.w = fmaxf(xv.w * sc + sh, 0.f);
    float4 o;
    o.x = xv.x + xqv.x + a.x * third + bsum;
    o.y = xv.y + xqv.y + a.y * third + bsum;
    o.z = xv.z + xqv.z + a.z * third + bsum;
    o.w = xv.w + xqv.w + a.w * third + bsum;
    *(float4*)(out + off) = o;
  }
}

extern "C" void kernel_launch(void* const* d_in, const int* in_sizes, int n_in,
                              void* d_out, int out_size, void* d_ws, size_t ws_size,
                              hipStream_t stream) {
  (void)in_sizes; (void)n_in; (void)out_size;
  const float* x    = (const float*)d_in[0];
  const float* xgi  = (const float*)d_in[1];
  const float* gn1w = (const float*)d_in[4];
  const float* gn1b = (const float*)d_in[5];
  const float* gn2w = (const float*)d_in[6];
  const float* gn2b = (const float*)d_in[7];
  const float* qw   = (const float*)d_in[8];
  const float* qb   = (const float*)d_in[9];
  const float* kw   = (const float*)d_in[10];
  const float* kb   = (const float*)d_in[11];
  const float* vw   = (const float*)d_in[12];
  const float* vb   = (const float*)d_in[13];
  const float* qgnw = (const float*)d_in[14];
  const float* qgnb = (const float*)d_in[15];
  const float* cw   = (const float*)d_in[16];
  const float* cb   = (const float*)d_in[17];

  float* ws = (float*)d_ws;
  __bf16* xq_t  = (__bf16*)ws;                    // 524288 bf16 (262144 f)
  __bf16* xg_t  = (__bf16*)(ws + 262144);         // 786432 bf16 (393216 f)
  __bf16* qwb   = (__bf16*)(ws + 655360);         // 49152 bf16 (24576 f)
  __bf16* kwb   = (__bf16*)(ws + 679936);         // 98304 bf16 (49152 f)
  __bf16* vwb   = (__bf16*)(ws + 729088);         // 98304 bf16 (49152 f)
  __bf16* q_raw = (__bf16*)(ws + 778240);         // 1572864 bf16 (786432 f)
  __bf16* k_raw = (__bf16*)(ws + 1564672);        // 393216 bf16 (196608 f)
  __bf16* v_raw = (__bf16*)(ws + 1761280);        // 393216 bf16 (196608 f)
  float*  ob    = ws + 1957888;                   // 1572864 f
  float*  accAll = ws + 3530752;                  // 256 f: [0,112) gn1/gn2, [112,256) qgn
  if (ws_size < (size_t)3531008 * sizeof(float)) return;

  float* qgnAcc = accAll + 112;
  float* outp = (float*)d_out;
  float* wout = outp + 524288;

  hipMemsetAsync(accAll, 0, 256 * sizeof(float), stream);

  pre_partial<<<640, 256, 0, stream>>>(x, xgi, accAll);

  stage_a<<<440, 256, 0, stream>>>(x, xgi, accAll, gn1w, gn1b, gn2w, gn2b,
                                   qw, kw, vw, xq_t, xg_t, qwb, kwb, vwb);

  proj_mfma<<<576, 256, 0, stream>>>(xq_t, xg_t, qwb, kwb, vwb, qb, kb, vb,
                                     q_raw, k_raw, v_raw, qgnAcc);

  qkv_affine<<<1152, 256, 0, stream>>>(q_raw, k_raw, v_raw, qgnAcc, qgnw, qgnb);

  attn_kernel<<<dim3(32, 8, 3), 256, 0, stream>>>(q_raw, k_raw, v_raw, ob, wout);

  combine_kernel<<<256, 256, 0, stream>>>(x, accAll, gn1w, gn1b, ob, cw, cb, outp);
}